// Round 5
// baseline (303.045 us; speedup 1.0000x reference)
//
#include <hip/hip_runtime.h>
#include <stdint.h>

// ---------------- types ----------------
using i32x4 = __attribute__((ext_vector_type(4))) int;
using f32x4 = __attribute__((ext_vector_type(4))) float;
using f16x4 = __attribute__((ext_vector_type(4))) _Float16;

#define M_TOK 8192
#define N_EMB 1024
#define D_FF  4096

__device__ __forceinline__ void async_lds16(void* lds, const void* g) {
  __builtin_amdgcn_global_load_lds(
      (const __attribute__((address_space(1))) void*)g,
      (__attribute__((address_space(3))) void*)lds, 16, 0, 0);
}

// ---------------- tiny init ----------------
__global__ void zero_slots_k(unsigned* s) {
  if (threadIdx.x < 16) s[threadIdx.x] = 0u;
}

// ---------------- global absmax (float bits atomicMax, order-independent) ----------------
__global__ void absmax_k(const float* __restrict__ p, long n, unsigned* __restrict__ slot) {
  long i = ((long)blockIdx.x * blockDim.x + threadIdx.x) * 4;
  long stride = (long)gridDim.x * blockDim.x * 4;
  float m = 0.f;
  for (; i < n; i += stride) {
    float4 v = *(const float4*)(p + i);
    m = fmaxf(m, fmaxf(fmaxf(fabsf(v.x), fabsf(v.y)), fmaxf(fabsf(v.z), fabsf(v.w))));
  }
  for (int o = 32; o; o >>= 1) m = fmaxf(m, __shfl_xor(m, o));
  __shared__ float sm[4];
  if ((threadIdx.x & 63) == 0) sm[threadIdx.x >> 6] = m;
  __syncthreads();
  if (threadIdx.x == 0) {
    m = fmaxf(fmaxf(sm[0], sm[1]), fmaxf(sm[2], sm[3]));
    atomicMax(slot, __float_as_uint(m));
  }
}

// ---------------- plain int8 quantization (weights) ----------------
__global__ void quant_k(const float* __restrict__ p, int8_t* __restrict__ q, long n,
                        const unsigned* __restrict__ slot) {
  float inv = 127.f / fmaxf(__uint_as_float(*slot), 1e-8f);
  long i = ((long)blockIdx.x * blockDim.x + threadIdx.x) * 4;
  long stride = (long)gridDim.x * blockDim.x * 4;
  for (; i < n; i += stride) {
    float4 v = *(const float4*)(p + i);
    int b0 = (int)fminf(fmaxf(rintf(v.x * inv), -127.f), 127.f);
    int b1 = (int)fminf(fmaxf(rintf(v.y * inv), -127.f), 127.f);
    int b2 = (int)fminf(fmaxf(rintf(v.z * inv), -127.f), 127.f);
    int b3 = (int)fminf(fmaxf(rintf(v.w * inv), -127.f), 127.f);
    int w = (b0 & 0xff) | ((b1 & 0xff) << 8) | ((b2 & 0xff) << 16) | ((b3 & 0xff) << 24);
    *(int*)(q + i) = w;
  }
}

// ---------------- pre-swizzle LoRA-down A[16][K] into per-lane MFMA B-fragments ----------------
__global__ void prep_bfrag_k(const float* __restrict__ A, _Float16* __restrict__ Bp, int K) {
  int s = blockIdx.x;
  int l = threadIdx.x;  // 64 threads
  int r = l & 15, g = l >> 4;
  float4 v = *(const float4*)(A + (long)r * K + s * 16 + g * 4);
  f16x4 h;
  h[0] = (_Float16)v.x; h[1] = (_Float16)v.y; h[2] = (_Float16)v.z; h[3] = (_Float16)v.w;
  *(f16x4*)(Bp + ((long)s * 64 + l) * 4) = h;
}

// ---------------- fused: quantize X rows to int8 AND T = 2 * X @ A^T via f16 MFMA ----------------
__global__ __launch_bounds__(512) void lora_quant_k(
    const float* __restrict__ X, const _Float16* __restrict__ Bpre,
    const unsigned* __restrict__ slot, int8_t* __restrict__ Q,
    float* __restrict__ T, int K) {
  int lane = threadIdx.x & 63, wave = threadIdx.x >> 6;
  int row0 = blockIdx.x * 16;
  int r = lane & 15, g = lane >> 4;
  float inv = 127.f / fmaxf(__uint_as_float(*slot), 1e-8f);

  int kPerWave = K >> 3;
  int kbase = wave * kPerWave;
  const float* xrow = X + (long)(row0 + r) * K;
  int8_t* qrow = Q + (long)(row0 + r) * K;

  f32x4 acc = {0.f, 0.f, 0.f, 0.f};
  int nsteps = kPerWave >> 4;
#pragma unroll 4
  for (int s = 0; s < nsteps; s++) {
    int k = kbase + s * 16 + g * 4;
    float4 v = *(const float4*)(xrow + k);
    int b0 = (int)fminf(fmaxf(rintf(v.x * inv), -127.f), 127.f);
    int b1 = (int)fminf(fmaxf(rintf(v.y * inv), -127.f), 127.f);
    int b2 = (int)fminf(fmaxf(rintf(v.z * inv), -127.f), 127.f);
    int b3 = (int)fminf(fmaxf(rintf(v.w * inv), -127.f), 127.f);
    *(int*)(qrow + k) = (b0 & 0xff) | ((b1 & 0xff) << 8) | ((b2 & 0xff) << 16) | ((b3 & 0xff) << 24);
    f16x4 a;
    a[0] = (_Float16)v.x; a[1] = (_Float16)v.y; a[2] = (_Float16)v.z; a[3] = (_Float16)v.w;
    int gs = (kbase + s * 16) >> 4;
    f16x4 b = *(const f16x4*)(Bpre + ((long)gs * 64 + lane) * 4);
    acc = __builtin_amdgcn_mfma_f32_16x16x16f16(a, b, acc, 0, 0, 0);
  }

  __shared__ float part[8][16][17];
#pragma unroll
  for (int j = 0; j < 4; j++) part[wave][g * 4 + j][r] = acc[j];
  __syncthreads();
  int t = threadIdx.x;
  if (t < 256) {
    int m = t >> 4, rr = t & 15;
    float sum = 0.f;
#pragma unroll
    for (int w = 0; w < 8; w++) sum += part[w][m][rr];
    T[(long)(row0 + m) * 16 + rr] = 2.0f * sum;  // LORA_SCALE = 32/16 = 2
  }
}

// ---------------- int8 GEMM: C = s*(Aq@Bq^T) + bias + T@Bl^T (+GELU) ----------------
// Exact m97-structure port to i8: BM=BN=128, BK=128 (128B rows = byte-identical to m97's
// bf16 BK=64), 256 threads (4 waves 2x2), SINGLE 32KB LDS buffer, plain __syncthreads()
// 2-barrier loop, ~3 blocks/CU for implicit wave-level overlap (m114).
// LDS tile [128 rows][8 x 16B slots], XOR-swizzled (slot c of row r at slot c^(r&7)):
// staged via linear-dest global_load_lds with inverse-permuted global source (8 lanes/row
// -> 128B contiguous segments); fragment ds_read_b128 is 2-way bank-aliased = free.
template <bool GELU>
__global__ __launch_bounds__(256, 3) void gemm_q8(
    const int8_t* __restrict__ Aq, const int8_t* __restrict__ Bq,
    int M, int N, int K,
    const unsigned* __restrict__ sa, const unsigned* __restrict__ sb,
    const float* __restrict__ bias,
    const float* __restrict__ T,   // [M][16], pre-scaled by LORA_SCALE
    const float* __restrict__ Bl,  // [N][16]
    float* __restrict__ C, unsigned* hmax) {
  __shared__ __align__(16) int8_t As[16384];
  __shared__ __align__(16) int8_t Bs[16384];

  int bn = blockIdx.x * 128;
  int bm = blockIdx.y * 128;

  int t = threadIdx.x;
  int lane = t & 63, wave = t >> 6;
  int wr = wave >> 1, wc = wave & 1;
  int l16 = lane & 15, lq = lane >> 4;

  // staging: 1024 slots of 16B per matrix / 256 threads = 4 gll each.
  // slot s = i*256+t: row = s>>3 (8 lanes/row), lds col = s&7, global col = (s&7)^(row&7).
  int ldst[4];
  const int8_t* srcA[4];
  const int8_t* srcB[4];
#pragma unroll
  for (int i = 0; i < 4; i++) {
    int s = i * 256 + t;
    int row = s >> 3;
    int cg = (s & 7) ^ (row & 7);
    ldst[i] = s * 16;
    srcA[i] = Aq + (long)(bm + row) * K + cg * 16;
    srcB[i] = Bq + (long)(bn + row) * K + cg * 16;
  }

  // fragment read byte-offsets for kh=0 (slots lq); kh=1 is ^64 (slot +4 = XOR 4)
  int aoff[4], boff[4];
#pragma unroll
  for (int mf = 0; mf < 4; mf++) {
    int row = wr * 64 + mf * 16 + l16;
    aoff[mf] = row * 128 + ((lq ^ (row & 7)) << 4);
  }
#pragma unroll
  for (int nf = 0; nf < 4; nf++) {
    int row = wc * 64 + nf * 16 + l16;
    boff[nf] = row * 128 + ((lq ^ (row & 7)) << 4);
  }

  i32x4 acc[4][4] = {};
  int KT = K >> 7;

  for (int kt = 0; kt < KT; ++kt) {
    long ko = (long)kt * 128;
#pragma unroll
    for (int i = 0; i < 4; i++) async_lds16(As + ldst[i], srcA[i] + ko);
#pragma unroll
    for (int i = 0; i < 4; i++) async_lds16(Bs + ldst[i], srcB[i] + ko);
    __syncthreads();

#pragma unroll
    for (int kh = 0; kh < 2; kh++) {
      int kx = kh << 6;  // slot c -> c^4 == byte offset ^64 within the row
      i32x4 av[4], bv[4];
#pragma unroll
      for (int mf = 0; mf < 4; mf++) av[mf] = *(const i32x4*)(As + (aoff[mf] ^ kx));
#pragma unroll
      for (int nf = 0; nf < 4; nf++) bv[nf] = *(const i32x4*)(Bs + (boff[nf] ^ kx));
#pragma unroll
      for (int mf = 0; mf < 4; mf++)
#pragma unroll
        for (int nf = 0; nf < 4; nf++)
          acc[mf][nf] = __builtin_amdgcn_mfma_i32_16x16x64_i8(av[mf], bv[nf], acc[mf][nf], 0, 0, 0);
    }
    __syncthreads();
  }

  // -------- epilogue --------
  float s = (fmaxf(__uint_as_float(*sa), 1e-8f) * (1.f / 127.f)) *
            (fmaxf(__uint_as_float(*sb), 1e-8f) * (1.f / 127.f));

  f16x4 af[4], bf[4];
#pragma unroll
  for (int mf = 0; mf < 4; mf++) {
    int m = bm + wr * 64 + mf * 16 + l16;
    float4 tv = *(const float4*)(T + (long)m * 16 + lq * 4);
    f16x4 v; v[0] = (_Float16)tv.x; v[1] = (_Float16)tv.y; v[2] = (_Float16)tv.z; v[3] = (_Float16)tv.w;
    af[mf] = v;
  }
#pragma unroll
  for (int nf = 0; nf < 4; nf++) {
    int n = bn + wc * 64 + nf * 16 + l16;
    float4 bv4 = *(const float4*)(Bl + (long)n * 16 + lq * 4);
    f16x4 v; v[0] = (_Float16)bv4.x; v[1] = (_Float16)bv4.y; v[2] = (_Float16)bv4.z; v[3] = (_Float16)bv4.w;
    bf[nf] = v;
  }
  float bias_v[4];
#pragma unroll
  for (int nf = 0; nf < 4; nf++) bias_v[nf] = bias[bn + wc * 64 + nf * 16 + l16];

  float lmax = 0.f;
#pragma unroll
  for (int mf = 0; mf < 4; mf++) {
#pragma unroll
    for (int nf = 0; nf < 4; nf++) {
      f32x4 fa = __builtin_amdgcn_mfma_f32_16x16x16f16(af[mf], bf[nf], f32x4{0.f, 0.f, 0.f, 0.f}, 0, 0, 0);
      int n = bn + wc * 64 + nf * 16 + l16;
#pragma unroll
      for (int j = 0; j < 4; j++) {
        int m = bm + wr * 64 + mf * 16 + lq * 4 + j;
        float v = s * (float)acc[mf][nf][j] + bias_v[nf] + fa[j];
        if constexpr (GELU) {
          v = 0.5f * v * (1.0f + erff(v * 0.70710678118654752f));
          lmax = fmaxf(lmax, fabsf(v));
        }
        C[(long)m * N + n] = v;
      }
    }
  }
  if constexpr (GELU) {
    for (int o = 32; o; o >>= 1) lmax = fmaxf(lmax, __shfl_xor(lmax, o));
    if (lane == 0) atomicMax(hmax, __float_as_uint(lmax));
  }
}

// ---------------- launch ----------------
extern "C" void kernel_launch(void* const* d_in, const int* in_sizes, int n_in,
                              void* d_out, int out_size, void* d_ws, size_t ws_size,
                              hipStream_t stream) {
  const float* x   = (const float*)d_in[0];
  const float* Wfc = (const float*)d_in[1];
  const float* bfc = (const float*)d_in[2];
  const float* Afc = (const float*)d_in[3];
  const float* Bfc = (const float*)d_in[4];
  const float* Wpj = (const float*)d_in[5];
  const float* bpj = (const float*)d_in[6];
  const float* Apj = (const float*)d_in[7];
  const float* Bpj = (const float*)d_in[8];
  float* out = (float*)d_out;

  char* ws = (char*)d_ws;
  unsigned* slots = (unsigned*)ws;  // [0]=max|x| [1]=max|Wfc| [2]=max|Wpj| [3]=max|h|
  int8_t* qx  = (int8_t*)(ws + 256);
  int8_t* qwf = qx  + (size_t)M_TOK * N_EMB;
  int8_t* qwp = qwf + (size_t)D_FF * N_EMB;
  int8_t* qh  = qwp + (size_t)N_EMB * D_FF;
  float*  t1  = (float*)(qh + (size_t)M_TOK * D_FF);
  float*  t2  = t1  + (size_t)M_TOK * 16;
  _Float16* Bp1 = (_Float16*)(t2 + (size_t)M_TOK * 16);
  _Float16* Bp2 = Bp1 + (size_t)N_EMB * 16;
  float*  h   = (float*)(Bp2 + (size_t)D_FF * 16);

  zero_slots_k<<<1, 64, 0, stream>>>(slots);
  absmax_k<<<1024, 256, 0, stream>>>(x,   (long)M_TOK * N_EMB, slots + 0);
  absmax_k<<<1024, 256, 0, stream>>>(Wfc, (long)D_FF * N_EMB,  slots + 1);
  absmax_k<<<1024, 256, 0, stream>>>(Wpj, (long)N_EMB * D_FF,  slots + 2);

  quant_k<<<2048, 256, 0, stream>>>(Wfc, qwf, (long)D_FF * N_EMB, slots + 1);
  quant_k<<<2048, 256, 0, stream>>>(Wpj, qwp, (long)N_EMB * D_FF, slots + 2);

  prep_bfrag_k<<<N_EMB / 16, 64, 0, stream>>>(Afc, Bp1, N_EMB);
  prep_bfrag_k<<<D_FF / 16, 64, 0, stream>>>(Apj, Bp2, D_FF);

  lora_quant_k<<<M_TOK / 16, 512, 0, stream>>>(x, Bp1, slots + 0, qx, t1, N_EMB);

  gemm_q8<true><<<dim3(D_FF / 128, M_TOK / 128), 256, 0, stream>>>(
      qx, qwf, M_TOK, D_FF, N_EMB, slots + 0, slots + 1, bfc, t1, Bfc, h, slots + 3);

  lora_quant_k<<<M_TOK / 16, 512, 0, stream>>>(h, Bp2, slots + 3, qh, t2, D_FF);

  gemm_q8<false><<<dim3(N_EMB / 128, M_TOK / 128), 256, 0, stream>>>(
      qh, qwp, M_TOK, N_EMB, D_FF, slots + 3, slots + 2, bpj, t2, Bpj, out, nullptr);
}